// Round 1
// baseline (1441.452 us; speedup 1.0000x reference)
//
#include <hip/hip_runtime.h>
#include <stdint.h>

// softmax((x@q)@(x@k)) @ (x@v), N=2048, fp32 in/out.
// Strategy: bf16 MFMA GEMMs with 3-term bf16 error-splitting (6 products) for the
// logit chain (fp32-quality: delta_S ~ 0.05 vs top-2 softmax gaps ~O(10^4)),
// plain bf16 for x@v and P@C (error ~0.2 << 4.46 threshold).
// GEMM: 128x128 tile, 16x16x32 bf16 MFMA, both operands staged k-contiguous
// (the "B" operand planes are produced pre-transposed by the split kernels).

#define TN 2048
static const int NB = TN;

typedef float f32x4 __attribute__((ext_vector_type(4)));
typedef short s16x8 __attribute__((ext_vector_type(8)));
typedef unsigned short u16x4 __attribute__((ext_vector_type(4)));
typedef unsigned int u32x4 __attribute__((ext_vector_type(4)));

// round-to-nearest-even fp32 -> bf16 (bit trick; inputs are finite, |v| < 1e6)
__device__ __forceinline__ unsigned short f2b(float f) {
    union { float f; unsigned int u; } c; c.f = f;
    unsigned int u = c.u + 0x7fffu + ((c.u >> 16) & 1u);
    return (unsigned short)(u >> 16);
}
__device__ __forceinline__ float b2f(unsigned short h) {
    union { unsigned int u; float f; } c; c.u = ((unsigned int)h) << 16;
    return c.f;
}

// ---------------- split kernels ----------------
// 3-term split: a ~= t0 + t1 + t2, residual ~2^-24 * |a|.

// plain (row-major out) — for A-operand planes
__global__ void split3_kernel(const float* __restrict__ in,
                              unsigned short* __restrict__ t0,
                              unsigned short* __restrict__ t1,
                              unsigned short* __restrict__ t2) {
    int i = (blockIdx.x * 256 + threadIdx.x) * 4;
    f32x4 f = *(const f32x4*)(in + i);
    u16x4 o0, o1, o2;
#pragma unroll
    for (int e = 0; e < 4; ++e) {
        float a = f[e];
        unsigned short h0 = f2b(a); float r1 = a - b2f(h0);
        unsigned short h1 = f2b(r1); float r2 = r1 - b2f(h1);
        o0[e] = h0; o1[e] = h1; o2[e] = f2b(r2);
    }
    *(u16x4*)(t0 + i) = o0; *(u16x4*)(t1 + i) = o1; *(u16x4*)(t2 + i) = o2;
}

// transposed out (out[c][r] = split(in[r][c])) — B-operand planes, LDS-tiled 64x64
__global__ void split3t_kernel(const float* __restrict__ in,
                               unsigned short* __restrict__ t0,
                               unsigned short* __restrict__ t1,
                               unsigned short* __restrict__ t2) {
    __shared__ unsigned short s0[64][68], s1[64][68], s2[64][68];
    int bc = blockIdx.x * 64;   // input col base
    int br = blockIdx.y * 64;   // input row base
    int tx = threadIdx.x & 15, ty = threadIdx.x >> 4;
#pragma unroll
    for (int rr = 0; rr < 64; rr += 16) {
        int r = rr + ty;
        f32x4 f = *(const f32x4*)(in + (size_t)(br + r) * TN + bc + tx * 4);
#pragma unroll
        for (int e = 0; e < 4; ++e) {
            float a = f[e];
            unsigned short h0 = f2b(a); float r1 = a - b2f(h0);
            unsigned short h1 = f2b(r1); float r2 = r1 - b2f(h1);
            s0[tx * 4 + e][r] = h0; s1[tx * 4 + e][r] = h1; s2[tx * 4 + e][r] = f2b(r2);
        }
    }
    __syncthreads();
#pragma unroll
    for (int rr = 0; rr < 64; rr += 16) {
        int c = rr + ty;
        u16x4 o0, o1, o2;
#pragma unroll
        for (int e = 0; e < 4; ++e) { o0[e] = s0[c][tx*4+e]; o1[e] = s1[c][tx*4+e]; o2[e] = s2[c][tx*4+e]; }
        size_t off = (size_t)(bc + c) * TN + br + tx * 4;
        *(u16x4*)(t0 + off) = o0; *(u16x4*)(t1 + off) = o1; *(u16x4*)(t2 + off) = o2;
    }
}

// single-term transposed cast (for v and C planes)
__global__ void cast1t_kernel(const float* __restrict__ in,
                              unsigned short* __restrict__ t0) {
    __shared__ unsigned short s0[64][68];
    int bc = blockIdx.x * 64;
    int br = blockIdx.y * 64;
    int tx = threadIdx.x & 15, ty = threadIdx.x >> 4;
#pragma unroll
    for (int rr = 0; rr < 64; rr += 16) {
        int r = rr + ty;
        f32x4 f = *(const f32x4*)(in + (size_t)(br + r) * TN + bc + tx * 4);
#pragma unroll
        for (int e = 0; e < 4; ++e) s0[tx * 4 + e][r] = f2b(f[e]);
    }
    __syncthreads();
#pragma unroll
    for (int rr = 0; rr < 64; rr += 16) {
        int c = rr + ty;
        u16x4 o0;
#pragma unroll
        for (int e = 0; e < 4; ++e) o0[e] = s0[c][tx*4+e];
        *(u16x4*)(t0 + (size_t)(bc + c) * TN + br + tx * 4) = o0;
    }
}

// ---------------- GEMM ----------------
// C[M,N] (+)= A @ B with A row-major [M,K] (k-contig) and Bt = B^T row-major
// [N,K] (k-contig). 128x128 block tile, BK=32, 4 waves in 2x2, each wave 64x64
// via 4x4 MFMA 16x16x32 tiles. LDS rows padded to 40 u16 (80 B: 16B-aligned
// b128 frag reads, <=2-way bank aliasing = free per m136).
__global__ __launch_bounds__(256) void gemm_bf16(const unsigned short* __restrict__ A,
                                                 const unsigned short* __restrict__ Bt,
                                                 float* __restrict__ C, int add) {
    __shared__ unsigned short lA[128][40];
    __shared__ unsigned short lB[128][40];
    const int tid = threadIdx.x;
    const int wave = tid >> 6, lane = tid & 63;
    const int wr = (wave >> 1) * 64, wc = (wave & 1) * 64;
    const int quad = lane >> 4, l16 = lane & 15;
    const int bm = blockIdx.y * 128, bn = blockIdx.x * 128;

    f32x4 acc[4][4];
#pragma unroll
    for (int i = 0; i < 4; ++i)
#pragma unroll
        for (int j = 0; j < 4; ++j) acc[i][j] = (f32x4){0.f, 0.f, 0.f, 0.f};

    for (int k0 = 0; k0 < TN; k0 += 32) {
        // stage: 128x32 u16 per tile = 512 16B-chunks, 2 per thread per tile
#pragma unroll
        for (int c = tid; c < 512; c += 256) {
            int r = c >> 2, ch = (c & 3) * 8;
            *(u32x4*)&lA[r][ch] = *(const u32x4*)(A + (size_t)(bm + r) * TN + k0 + ch);
            *(u32x4*)&lB[r][ch] = *(const u32x4*)(Bt + (size_t)(bn + r) * TN + k0 + ch);
        }
        __syncthreads();
        s16x8 af[4], bf[4];
#pragma unroll
        for (int i = 0; i < 4; ++i) af[i] = *(const s16x8*)&lA[wr + i * 16 + l16][quad * 8];
#pragma unroll
        for (int j = 0; j < 4; ++j) bf[j] = *(const s16x8*)&lB[wc + j * 16 + l16][quad * 8];
#pragma unroll
        for (int i = 0; i < 4; ++i)
#pragma unroll
            for (int j = 0; j < 4; ++j)
                acc[i][j] = __builtin_amdgcn_mfma_f32_16x16x32_bf16(af[i], bf[j], acc[i][j], 0, 0, 0);
        __syncthreads();
    }
    // epilogue: C/D layout col=lane&15, row=quad*4+reg (verified m89/m91)
#pragma unroll
    for (int i = 0; i < 4; ++i)
#pragma unroll
        for (int j = 0; j < 4; ++j) {
            int row = bm + wr + i * 16 + quad * 4;
            int col = bn + wc + j * 16 + l16;
            float* p = C + (size_t)row * TN + col;
#pragma unroll
            for (int r = 0; r < 4; ++r) {
                float vv = acc[i][j][r];
                if (add) p[(size_t)r * TN] += vv; else p[(size_t)r * TN] = vv;
            }
        }
}

// ---------------- softmax (row-wise, fp32, writes bf16 P) ----------------
__global__ void softmax_kernel(const float* __restrict__ S, unsigned short* __restrict__ P) {
    __shared__ float red[256];
    const int row = blockIdx.x, tid = threadIdx.x;
    const float* s = S + (size_t)row * TN;
    float m = -3.4e38f;
    for (int c = tid; c < TN; c += 256) m = fmaxf(m, s[c]);
    red[tid] = m; __syncthreads();
    for (int st = 128; st > 0; st >>= 1) { if (tid < st) red[tid] = fmaxf(red[tid], red[tid + st]); __syncthreads(); }
    m = red[0]; __syncthreads();
    float sum = 0.f;
    for (int c = tid; c < TN; c += 256) sum += expf(s[c] - m);
    red[tid] = sum; __syncthreads();
    for (int st = 128; st > 0; st >>= 1) { if (tid < st) red[tid] += red[tid + st]; __syncthreads(); }
    float inv = 1.f / red[0];
    unsigned short* p = P + (size_t)row * TN;
    for (int c = tid; c < TN; c += 256) p[c] = f2b(expf(s[c] - m) * inv);
}

extern "C" void kernel_launch(void* const* d_in, const int* in_sizes, int n_in,
                              void* d_out, int out_size, void* d_ws, size_t ws_size,
                              hipStream_t stream) {
    const float* x = (const float*)d_in[0];
    const float* q = (const float*)d_in[1];
    const float* k = (const float*)d_in[2];
    const float* v = (const float*)d_in[3];
    float* out = (float*)d_out;
    const size_t M = (size_t)TN * TN;

    // ws layout: 1 fp32 buffer (16.8 MB) + 10 bf16 planes (8.4 MB each) = ~100.7 MB
    // d_out doubles as the second fp32 scratch (holds A, then S, then final out).
    float* F2 = (float*)d_ws;
    unsigned short* pl = (unsigned short*)(F2 + M);
    unsigned short *x0 = pl,        *x1 = pl + M,   *x2 = pl + 2*M;
    unsigned short *q0 = pl + 3*M,  *q1 = pl + 4*M, *q2 = pl + 5*M;  // T planes; reused as a-planes
    unsigned short *k0 = pl + 6*M,  *k1 = pl + 7*M, *k2 = pl + 8*M;  // T planes; reused as b-planes
    unsigned short *v0 = pl + 9*M;                                    // T plane
    unsigned short *a0 = q0, *a1 = q1, *a2 = q2;   // plain planes (A-operand)
    unsigned short *b0 = k0, *b1 = k1, *b2 = k2;   // T planes (B-operand)
    unsigned short *p0 = x1, *c0 = x2;             // reuse after x1/x2 done

    dim3 bs(256);
    dim3 gsplit(TN * TN / 4 / 256);   // 4096
    dim3 gt(TN / 64, TN / 64);        // 32x32
    dim3 gg(TN / 128, TN / 128);      // 16x16

#define GEMM(Ap, Bp, Cp, addf) hipLaunchKernelGGL(gemm_bf16, gg, bs, 0, stream, Ap, Bp, Cp, addf)

    // splits of inputs
    hipLaunchKernelGGL(split3_kernel,  gsplit, bs, 0, stream, x, x0, x1, x2);
    hipLaunchKernelGGL(split3t_kernel, gt,     bs, 0, stream, q, q0, q1, q2);
    // A = x@q  (6 products: (0,0)(0,1)(1,0)(1,1)(0,2)(2,0)) -> d_out
    GEMM(x0, q0, out, 0); GEMM(x0, q1, out, 1); GEMM(x1, q0, out, 1);
    GEMM(x1, q1, out, 1); GEMM(x0, q2, out, 1); GEMM(x2, q0, out, 1);
    // B = x@k -> F2
    hipLaunchKernelGGL(split3t_kernel, gt, bs, 0, stream, k, k0, k1, k2);
    GEMM(x0, k0, F2, 0); GEMM(x0, k1, F2, 1); GEMM(x1, k0, F2, 1);
    GEMM(x1, k1, F2, 1); GEMM(x0, k2, F2, 1); GEMM(x2, k0, F2, 1);
    // split A (in d_out) -> a-planes (plain); split B (F2) -> b-planes (T)
    hipLaunchKernelGGL(split3_kernel,  gsplit, bs, 0, stream, out, a0, a1, a2);
    hipLaunchKernelGGL(split3t_kernel, gt,     bs, 0, stream, F2, b0, b1, b2);
    // S = A@B -> d_out (A was already split; safe to overwrite)
    GEMM(a0, b0, out, 0); GEMM(a0, b1, out, 1); GEMM(a1, b0, out, 1);
    GEMM(a1, b1, out, 1); GEMM(a0, b2, out, 1); GEMM(a2, b0, out, 1);
    // P = softmax(S) -> bf16 p0
    hipLaunchKernelGGL(softmax_kernel, dim3(TN), bs, 0, stream, out, p0);
    // C = x@v -> F2 (overwrites B; b-planes already extracted)
    hipLaunchKernelGGL(cast1t_kernel, gt, bs, 0, stream, v, v0);
    GEMM(x0, v0, F2, 0);
    hipLaunchKernelGGL(cast1t_kernel, gt, bs, 0, stream, F2, c0);
    // out = P@C -> d_out
    GEMM(p0, c0, out, 0);
#undef GEMM
}

// Round 2
// 658.087 us; speedup vs baseline: 2.1904x; 2.1904x over previous
//
#include <hip/hip_runtime.h>
#include <stdint.h>

// softmax((x@q)@(x@k)) @ (x@v), N=2048, fp32 in/out.
// R2: fused 6-product split-GEMM (gemm6), 128x64 tiles (grid 512 = 2 blocks/CU),
// global_load_lds width-16 staging into XOR-swizzled LDS (conflict-free frag reads).
// Numerics: 3-term bf16 splits for the logit chain (passed R1 with absmax 1.0),
// plain bf16 for x@v and P@C.

#define TN 2048

typedef float f32x4 __attribute__((ext_vector_type(4)));
typedef short s16x8 __attribute__((ext_vector_type(8)));
typedef unsigned short u16x4 __attribute__((ext_vector_type(4)));

__device__ __forceinline__ unsigned short f2b(float f) {
    union { float f; unsigned int u; } c; c.f = f;
    unsigned int u = c.u + 0x7fffu + ((c.u >> 16) & 1u);
    return (unsigned short)(u >> 16);
}
__device__ __forceinline__ float b2f(unsigned short h) {
    union { unsigned int u; float f; } c; c.u = ((unsigned int)h) << 16;
    return c.f;
}

// async global->LDS, 16B per lane; LDS dest = wave-uniform base + lane*16
__device__ __forceinline__ void gll16(const unsigned short* g, unsigned short* l) {
    __builtin_amdgcn_global_load_lds(
        (const __attribute__((address_space(1))) unsigned int*)g,
        (__attribute__((address_space(3))) unsigned int*)l, 16, 0, 0);
}

// ---------------- split kernels ----------------
__global__ void split3_kernel(const float* __restrict__ in,
                              unsigned short* __restrict__ t0,
                              unsigned short* __restrict__ t1,
                              unsigned short* __restrict__ t2) {
    int i = (blockIdx.x * 256 + threadIdx.x) * 4;
    f32x4 f = *(const f32x4*)(in + i);
    u16x4 o0, o1, o2;
#pragma unroll
    for (int e = 0; e < 4; ++e) {
        float a = f[e];
        unsigned short h0 = f2b(a); float r1 = a - b2f(h0);
        unsigned short h1 = f2b(r1); float r2 = r1 - b2f(h1);
        o0[e] = h0; o1[e] = h1; o2[e] = f2b(r2);
    }
    *(u16x4*)(t0 + i) = o0; *(u16x4*)(t1 + i) = o1; *(u16x4*)(t2 + i) = o2;
}

__global__ void split3t_kernel(const float* __restrict__ in,
                               unsigned short* __restrict__ t0,
                               unsigned short* __restrict__ t1,
                               unsigned short* __restrict__ t2) {
    __shared__ unsigned short s0[64][68], s1[64][68], s2[64][68];
    int bc = blockIdx.x * 64, br = blockIdx.y * 64;
    int tx = threadIdx.x & 15, ty = threadIdx.x >> 4;
#pragma unroll
    for (int rr = 0; rr < 64; rr += 16) {
        int r = rr + ty;
        f32x4 f = *(const f32x4*)(in + (size_t)(br + r) * TN + bc + tx * 4);
#pragma unroll
        for (int e = 0; e < 4; ++e) {
            float a = f[e];
            unsigned short h0 = f2b(a); float r1 = a - b2f(h0);
            unsigned short h1 = f2b(r1); float r2 = r1 - b2f(h1);
            s0[tx * 4 + e][r] = h0; s1[tx * 4 + e][r] = h1; s2[tx * 4 + e][r] = f2b(r2);
        }
    }
    __syncthreads();
#pragma unroll
    for (int rr = 0; rr < 64; rr += 16) {
        int c = rr + ty;
        u16x4 o0, o1, o2;
#pragma unroll
        for (int e = 0; e < 4; ++e) { o0[e] = s0[c][tx*4+e]; o1[e] = s1[c][tx*4+e]; o2[e] = s2[c][tx*4+e]; }
        size_t off = (size_t)(bc + c) * TN + br + tx * 4;
        *(u16x4*)(t0 + off) = o0; *(u16x4*)(t1 + off) = o1; *(u16x4*)(t2 + off) = o2;
    }
}

__global__ void cast1t_kernel(const float* __restrict__ in,
                              unsigned short* __restrict__ t0) {
    __shared__ unsigned short s0[64][68];
    int bc = blockIdx.x * 64, br = blockIdx.y * 64;
    int tx = threadIdx.x & 15, ty = threadIdx.x >> 4;
#pragma unroll
    for (int rr = 0; rr < 64; rr += 16) {
        int r = rr + ty;
        f32x4 f = *(const f32x4*)(in + (size_t)(br + r) * TN + bc + tx * 4);
#pragma unroll
        for (int e = 0; e < 4; ++e) s0[tx * 4 + e][r] = f2b(f[e]);
    }
    __syncthreads();
#pragma unroll
    for (int rr = 0; rr < 64; rr += 16) {
        int c = rr + ty;
        u16x4 o0;
#pragma unroll
        for (int e = 0; e < 4; ++e) o0[e] = s0[c][tx*4+e];
        *(u16x4*)(t0 + (size_t)(bc + c) * TN + br + tx * 4) = o0;
    }
}

// ---------------- fused 6-product GEMM ----------------
// C = sum of 6 split products of A@B. A-planes row-major [M,K]; B-planes = B^T
// row-major [N,K]. Tile 128(M)x64(N), BK=32, 4 waves 2x2 (wave: 64x32 = 4x2
// MFMA tiles). LDS: unpadded 64B rows, chunk c of row r stored at slot c^(r&3)
// -> global_load_lds-compatible AND bank-balanced b128 frag reads.
__global__ __launch_bounds__(256, 2) void gemm6_bf16(
    const unsigned short* __restrict__ a0p, const unsigned short* __restrict__ a1p,
    const unsigned short* __restrict__ a2p,
    const unsigned short* __restrict__ b0p, const unsigned short* __restrict__ b1p,
    const unsigned short* __restrict__ b2p,
    float* __restrict__ C) {
    __shared__ unsigned short lds[(3 * 128 + 3 * 64) * 32];  // 36 KB
    const int tid = threadIdx.x;
    const int wave = tid >> 6, lane = tid & 63;
    const int wr = (wave >> 1) * 64, wc = (wave & 1) * 32;
    const int quad = lane >> 4, l16 = lane & 15;
    const int bm = blockIdx.y * 128, bn = blockIdx.x * 64;
    const int rl = lane >> 2;          // staging row within 16-row segment
    const int cg = (lane & 3) ^ (rl & 3);  // global chunk fetched into slot lane&3

    const unsigned short* Ap[3] = {a0p, a1p, a2p};
    const unsigned short* Bp[3] = {b0p, b1p, b2p};

    f32x4 acc[4][2];
#pragma unroll
    for (int i = 0; i < 4; ++i)
#pragma unroll
        for (int j = 0; j < 2; ++j) acc[i][j] = (f32x4){0.f, 0.f, 0.f, 0.f};

    for (int k0 = 0; k0 < TN; k0 += 32) {
        // 36 wave-segments: 24 A (3 planes x 8) + 12 B (3 planes x 4), 16 rows each
        for (int t = wave; t < 36; t += 4) {
            const unsigned short* src;
            unsigned short* dst;
            if (t < 24) {
                int p = t >> 3, seg = t & 7;
                src = Ap[p] + (size_t)(bm + seg * 16 + rl) * TN + k0 + cg * 8;
                dst = lds + (p * 128 + seg * 16) * 32;
            } else {
                int u = t - 24, p = u >> 2, seg = u & 3;
                src = Bp[p] + (size_t)(bn + seg * 16 + rl) * TN + k0 + cg * 8;
                dst = lds + (3 * 128 + p * 64 + seg * 16) * 32;
            }
            gll16(src, dst);
        }
        __syncthreads();  // drains vmcnt (global_load_lds) + barrier

        const unsigned short* lA = lds;
        const unsigned short* lB = lds + 3 * 128 * 32;
        s16x8 af[3][4], bf[3][2];
#pragma unroll
        for (int p = 0; p < 3; ++p) {
#pragma unroll
            for (int i = 0; i < 4; ++i) {
                int row = wr + i * 16 + l16;
                af[p][i] = *(const s16x8*)(lA + (p * 128 + row) * 32 + ((quad ^ (row & 3)) * 8));
            }
#pragma unroll
            for (int j = 0; j < 2; ++j) {
                int row = wc + j * 16 + l16;
                bf[p][j] = *(const s16x8*)(lB + (p * 64 + row) * 32 + ((quad ^ (row & 3)) * 8));
            }
        }
#pragma unroll
        for (int i = 0; i < 4; ++i)
#pragma unroll
            for (int j = 0; j < 2; ++j) {
                f32x4 a = acc[i][j];
                a = __builtin_amdgcn_mfma_f32_16x16x32_bf16(af[0][i], bf[0][j], a, 0, 0, 0);
                a = __builtin_amdgcn_mfma_f32_16x16x32_bf16(af[0][i], bf[1][j], a, 0, 0, 0);
                a = __builtin_amdgcn_mfma_f32_16x16x32_bf16(af[1][i], bf[0][j], a, 0, 0, 0);
                a = __builtin_amdgcn_mfma_f32_16x16x32_bf16(af[1][i], bf[1][j], a, 0, 0, 0);
                a = __builtin_amdgcn_mfma_f32_16x16x32_bf16(af[0][i], bf[2][j], a, 0, 0, 0);
                a = __builtin_amdgcn_mfma_f32_16x16x32_bf16(af[2][i], bf[0][j], a, 0, 0, 0);
                acc[i][j] = a;
            }
        __syncthreads();
    }
    // epilogue: C/D layout col=lane&15, row=quad*4+reg (verified m89/m91)
#pragma unroll
    for (int i = 0; i < 4; ++i)
#pragma unroll
        for (int j = 0; j < 2; ++j) {
            int row = bm + wr + i * 16 + quad * 4;
            int col = bn + wc + j * 16 + l16;
            float* p = C + (size_t)row * TN + col;
#pragma unroll
            for (int r = 0; r < 4; ++r) p[(size_t)r * TN] = acc[i][j][r];
        }
}

// ---------------- single-product GEMM (same structure) ----------------
__global__ __launch_bounds__(256, 2) void gemm1_bf16(
    const unsigned short* __restrict__ A, const unsigned short* __restrict__ Bt,
    float* __restrict__ C) {
    __shared__ unsigned short lds[(128 + 64) * 32];  // 12 KB
    const int tid = threadIdx.x;
    const int wave = tid >> 6, lane = tid & 63;
    const int wr = (wave >> 1) * 64, wc = (wave & 1) * 32;
    const int quad = lane >> 4, l16 = lane & 15;
    const int bm = blockIdx.y * 128, bn = blockIdx.x * 64;
    const int rl = lane >> 2;
    const int cg = (lane & 3) ^ (rl & 3);

    f32x4 acc[4][2];
#pragma unroll
    for (int i = 0; i < 4; ++i)
#pragma unroll
        for (int j = 0; j < 2; ++j) acc[i][j] = (f32x4){0.f, 0.f, 0.f, 0.f};

    for (int k0 = 0; k0 < TN; k0 += 32) {
        for (int t = wave; t < 12; t += 4) {
            const unsigned short* src;
            unsigned short* dst;
            if (t < 8) {
                src = A + (size_t)(bm + t * 16 + rl) * TN + k0 + cg * 8;
                dst = lds + (t * 16) * 32;
            } else {
                int seg = t - 8;
                src = Bt + (size_t)(bn + seg * 16 + rl) * TN + k0 + cg * 8;
                dst = lds + (128 + seg * 16) * 32;
            }
            gll16(src, dst);
        }
        __syncthreads();

        const unsigned short* lA = lds;
        const unsigned short* lB = lds + 128 * 32;
        s16x8 af[4], bf[2];
#pragma unroll
        for (int i = 0; i < 4; ++i) {
            int row = wr + i * 16 + l16;
            af[i] = *(const s16x8*)(lA + row * 32 + ((quad ^ (row & 3)) * 8));
        }
#pragma unroll
        for (int j = 0; j < 2; ++j) {
            int row = wc + j * 16 + l16;
            bf[j] = *(const s16x8*)(lB + row * 32 + ((quad ^ (row & 3)) * 8));
        }
#pragma unroll
        for (int i = 0; i < 4; ++i)
#pragma unroll
            for (int j = 0; j < 2; ++j)
                acc[i][j] = __builtin_amdgcn_mfma_f32_16x16x32_bf16(af[i], bf[j], acc[i][j], 0, 0, 0);
        __syncthreads();
    }
#pragma unroll
    for (int i = 0; i < 4; ++i)
#pragma unroll
        for (int j = 0; j < 2; ++j) {
            int row = bm + wr + i * 16 + quad * 4;
            int col = bn + wc + j * 16 + l16;
            float* p = C + (size_t)row * TN + col;
#pragma unroll
            for (int r = 0; r < 4; ++r) p[(size_t)r * TN] = acc[i][j][r];
        }
}

// ---------------- softmax ----------------
__global__ void softmax_kernel(const float* __restrict__ S, unsigned short* __restrict__ P) {
    __shared__ float red[256];
    const int row = blockIdx.x, tid = threadIdx.x;
    const float* s = S + (size_t)row * TN;
    float m = -3.4e38f;
    for (int c = tid; c < TN; c += 256) m = fmaxf(m, s[c]);
    red[tid] = m; __syncthreads();
    for (int st = 128; st > 0; st >>= 1) { if (tid < st) red[tid] = fmaxf(red[tid], red[tid + st]); __syncthreads(); }
    m = red[0]; __syncthreads();
    float sum = 0.f;
    for (int c = tid; c < TN; c += 256) sum += expf(s[c] - m);
    red[tid] = sum; __syncthreads();
    for (int st = 128; st > 0; st >>= 1) { if (tid < st) red[tid] += red[tid + st]; __syncthreads(); }
    float inv = 1.f / red[0];
    unsigned short* p = P + (size_t)row * TN;
    for (int c = tid; c < TN; c += 256) p[c] = f2b(expf(s[c] - m) * inv);
}

extern "C" void kernel_launch(void* const* d_in, const int* in_sizes, int n_in,
                              void* d_out, int out_size, void* d_ws, size_t ws_size,
                              hipStream_t stream) {
    const float* x = (const float*)d_in[0];
    const float* q = (const float*)d_in[1];
    const float* k = (const float*)d_in[2];
    const float* v = (const float*)d_in[3];
    float* out = (float*)d_out;
    const size_t M = (size_t)TN * TN;

    float* F2 = (float*)d_ws;
    unsigned short* pl = (unsigned short*)(F2 + M);
    unsigned short *x0 = pl,        *x1 = pl + M,   *x2 = pl + 2*M;
    unsigned short *q0 = pl + 3*M,  *q1 = pl + 4*M, *q2 = pl + 5*M;
    unsigned short *k0 = pl + 6*M,  *k1 = pl + 7*M, *k2 = pl + 8*M;
    unsigned short *v0 = pl + 9*M;
    unsigned short *a0 = q0, *a1 = q1, *a2 = q2;   // reuse q planes
    unsigned short *b0 = k0, *b1 = k1, *b2 = k2;   // reuse k planes
    unsigned short *p0 = x1, *c0 = x2;             // reuse x1/x2 after B-chain

    dim3 bs(256);
    dim3 gsplit(TN * TN / 4 / 256);
    dim3 gt(TN / 64, TN / 64);
    dim3 gg(TN / 64, TN / 128);   // 32 x 16 = 512 blocks

    hipLaunchKernelGGL(split3_kernel,  gsplit, bs, 0, stream, x, x0, x1, x2);
    hipLaunchKernelGGL(split3t_kernel, gt,     bs, 0, stream, q, q0, q1, q2);
    // A = x@q -> d_out
    hipLaunchKernelGGL(gemm6_bf16, gg, bs, 0, stream, x0, x1, x2, q0, q1, q2, out);
    hipLaunchKernelGGL(split3t_kernel, gt, bs, 0, stream, k, k0, k1, k2);
    // B = x@k -> F2
    hipLaunchKernelGGL(gemm6_bf16, gg, bs, 0, stream, x0, x1, x2, k0, k1, k2, F2);
    // split A and B
    hipLaunchKernelGGL(split3_kernel,  gsplit, bs, 0, stream, out, a0, a1, a2);
    hipLaunchKernelGGL(split3t_kernel, gt,     bs, 0, stream, F2, b0, b1, b2);
    // S = A@B -> d_out
    hipLaunchKernelGGL(gemm6_bf16, gg, bs, 0, stream, a0, a1, a2, b0, b1, b2, out);
    // P = softmax(S) -> p0
    hipLaunchKernelGGL(softmax_kernel, dim3(TN), bs, 0, stream, out, p0);
    // C = x@v -> F2
    hipLaunchKernelGGL(cast1t_kernel, gt, bs, 0, stream, v, v0);
    hipLaunchKernelGGL(gemm1_bf16, gg, bs, 0, stream, x0, v0, F2);
    hipLaunchKernelGGL(cast1t_kernel, gt, bs, 0, stream, F2, c0);
    // out = P@C
    hipLaunchKernelGGL(gemm1_bf16, gg, bs, 0, stream, p0, c0, out);
}

// Round 3
// 562.058 us; speedup vs baseline: 2.5646x; 1.1709x over previous
//
#include <hip/hip_runtime.h>
#include <stdint.h>

// softmax((x@q)@(x@k)) @ (x@v), N=2048, fp32 in/out.
// R3: gemm at 128x128 / wave tile 64x64 (64 FLOP per LDS byte), register-prefetch
// pipeline (hoisted per-thread src pointers, global->VGPR->ds_write_b128),
// bank-group-exact LDS swizzle slot(row,chunk)=row*4+((chunk+row+(row>>2))&3).
// Numerics unchanged: 3-term bf16 splits, 6 products for the logit chain.

#define TN 2048

typedef float f32x4 __attribute__((ext_vector_type(4)));
typedef short s16x8 __attribute__((ext_vector_type(8)));
typedef unsigned short u16x4 __attribute__((ext_vector_type(4)));
typedef unsigned int u32x4 __attribute__((ext_vector_type(4)));

__device__ __forceinline__ unsigned short f2b(float f) {
    union { float f; unsigned int u; } c; c.f = f;
    unsigned int u = c.u + 0x7fffu + ((c.u >> 16) & 1u);
    return (unsigned short)(u >> 16);
}
__device__ __forceinline__ float b2f(unsigned short h) {
    union { unsigned int u; float f; } c; c.u = ((unsigned int)h) << 16;
    return c.f;
}

#define MFMA(a, b, c) __builtin_amdgcn_mfma_f32_16x16x32_bf16(a, b, c, 0, 0, 0)

// ---------------- split kernels (unchanged) ----------------
__global__ void split3_kernel(const float* __restrict__ in,
                              unsigned short* __restrict__ t0,
                              unsigned short* __restrict__ t1,
                              unsigned short* __restrict__ t2) {
    int i = (blockIdx.x * 256 + threadIdx.x) * 4;
    f32x4 f = *(const f32x4*)(in + i);
    u16x4 o0, o1, o2;
#pragma unroll
    for (int e = 0; e < 4; ++e) {
        float a = f[e];
        unsigned short h0 = f2b(a); float r1 = a - b2f(h0);
        unsigned short h1 = f2b(r1); float r2 = r1 - b2f(h1);
        o0[e] = h0; o1[e] = h1; o2[e] = f2b(r2);
    }
    *(u16x4*)(t0 + i) = o0; *(u16x4*)(t1 + i) = o1; *(u16x4*)(t2 + i) = o2;
}

__global__ void split3t_kernel(const float* __restrict__ in,
                               unsigned short* __restrict__ t0,
                               unsigned short* __restrict__ t1,
                               unsigned short* __restrict__ t2) {
    __shared__ unsigned short s0[64][68], s1[64][68], s2[64][68];
    int bc = blockIdx.x * 64, br = blockIdx.y * 64;
    int tx = threadIdx.x & 15, ty = threadIdx.x >> 4;
#pragma unroll
    for (int rr = 0; rr < 64; rr += 16) {
        int r = rr + ty;
        f32x4 f = *(const f32x4*)(in + (size_t)(br + r) * TN + bc + tx * 4);
#pragma unroll
        for (int e = 0; e < 4; ++e) {
            float a = f[e];
            unsigned short h0 = f2b(a); float r1 = a - b2f(h0);
            unsigned short h1 = f2b(r1); float r2 = r1 - b2f(h1);
            s0[tx * 4 + e][r] = h0; s1[tx * 4 + e][r] = h1; s2[tx * 4 + e][r] = f2b(r2);
        }
    }
    __syncthreads();
#pragma unroll
    for (int rr = 0; rr < 64; rr += 16) {
        int c = rr + ty;
        u16x4 o0, o1, o2;
#pragma unroll
        for (int e = 0; e < 4; ++e) { o0[e] = s0[c][tx*4+e]; o1[e] = s1[c][tx*4+e]; o2[e] = s2[c][tx*4+e]; }
        size_t off = (size_t)(bc + c) * TN + br + tx * 4;
        *(u16x4*)(t0 + off) = o0; *(u16x4*)(t1 + off) = o1; *(u16x4*)(t2 + off) = o2;
    }
}

__global__ void cast1t_kernel(const float* __restrict__ in,
                              unsigned short* __restrict__ t0) {
    __shared__ unsigned short s0[64][68];
    int bc = blockIdx.x * 64, br = blockIdx.y * 64;
    int tx = threadIdx.x & 15, ty = threadIdx.x >> 4;
#pragma unroll
    for (int rr = 0; rr < 64; rr += 16) {
        int r = rr + ty;
        f32x4 f = *(const f32x4*)(in + (size_t)(br + r) * TN + bc + tx * 4);
#pragma unroll
        for (int e = 0; e < 4; ++e) s0[tx * 4 + e][r] = f2b(f[e]);
    }
    __syncthreads();
#pragma unroll
    for (int rr = 0; rr < 64; rr += 16) {
        int c = rr + ty;
        u16x4 o0;
#pragma unroll
        for (int e = 0; e < 4; ++e) o0[e] = s0[c][tx*4+e];
        *(u16x4*)(t0 + (size_t)(bc + c) * TN + br + tx * 4) = o0;
    }
}

// ---------------- fused 6-product GEMM, 128x128 ----------------
// 48 LDS segments of 1024 B: segs 0..23 = A planes (p*8+blk), 24..47 = B planes.
// Segment holds 16 rows x 32 u16 (one BK=32 slab). Slot i (16 B) of a segment
// holds (row=i>>2, chunk=cg(i)); reads find (row,chunk q) at
// row*4 + ((q+row+(row>>2))&3)  ->  8 distinct bank-groups per 8-lane phase.
__global__ __launch_bounds__(256, 1) void gemm6_bf16(
    const unsigned short* __restrict__ a0p, const unsigned short* __restrict__ a1p,
    const unsigned short* __restrict__ a2p,
    const unsigned short* __restrict__ b0p, const unsigned short* __restrict__ b1p,
    const unsigned short* __restrict__ b2p,
    float* __restrict__ C) {
    __shared__ unsigned short lds[48 * 512];  // 48 KB
    const int tid = threadIdx.x;
    const int wave = tid >> 6, lane = tid & 63;
    const int wr = (wave >> 1) * 64, wc = (wave & 1) * 64;
    const int quad = lane >> 4, l16 = lane & 15;
    const int bm = blockIdx.y * 128, bn = blockIdx.x * 128;

    // staging: per-wave 12 segments; per-lane row + fetched chunk
    const int srow = lane >> 2;
    const int cg = ((lane & 3) - (lane >> 2) - (lane >> 4)) & 3;
    const unsigned short* Ap[3] = {a0p, a1p, a2p};
    const unsigned short* Bp[3] = {b0p, b1p, b2p};
    const unsigned short* sp[12];
#pragma unroll
    for (int t = 0; t < 12; ++t) {
        int s = wave * 12 + t;
        int isA = s < 24;
        int u = isA ? s : (s - 24);
        int p = u >> 3, seg = u & 7;
        const unsigned short* base = isA ? Ap[p] : Bp[p];
        int gr = (isA ? bm : bn) + seg * 16 + srow;
        sp[t] = base + (size_t)gr * TN + cg * 8;
    }
    unsigned short* dbase = lds + wave * 12 * 512 + lane * 8;
    // read pointers: within-segment lane offset (u16 units)
    const int rdoff = l16 * 32 + ((quad + l16 + (l16 >> 2)) & 3) * 8;
    const unsigned short* rdA = lds + rdoff + (wr >> 4) * 512;
    const unsigned short* rdB = lds + rdoff + (24 + (wc >> 4)) * 512;

    f32x4 acc[4][4];
#pragma unroll
    for (int i = 0; i < 4; ++i)
#pragma unroll
        for (int j = 0; j < 4; ++j) acc[i][j] = (f32x4){0.f, 0.f, 0.f, 0.f};

    u32x4 g[12];
#pragma unroll
    for (int t = 0; t < 12; ++t) { g[t] = *(const u32x4*)sp[t]; sp[t] += 32; }

    for (int k0 = 0; k0 < 64; ++k0) {
        __syncthreads();  // prior compute's reads done -> LDS writable
#pragma unroll
        for (int t = 0; t < 12; ++t) *(u32x4*)(dbase + t * 512) = g[t];
        if (k0 < 63) {
#pragma unroll
            for (int t = 0; t < 12; ++t) { g[t] = *(const u32x4*)sp[t]; sp[t] += 32; }
        }
        __syncthreads();  // staged tile visible

        s16x8 bfr[3][4];
#pragma unroll
        for (int p = 0; p < 3; ++p)
#pragma unroll
            for (int j = 0; j < 4; ++j)
                bfr[p][j] = *(const s16x8*)(rdB + (p * 8 + j) * 512);
#pragma unroll
        for (int i = 0; i < 4; ++i) {
            s16x8 a0 = *(const s16x8*)(rdA + (0 + i) * 512);
            s16x8 a1 = *(const s16x8*)(rdA + (8 + i) * 512);
            s16x8 a2 = *(const s16x8*)(rdA + (16 + i) * 512);
#pragma unroll
            for (int j = 0; j < 4; ++j) {
                f32x4 c = acc[i][j];
                c = MFMA(a0, bfr[0][j], c);
                c = MFMA(a0, bfr[1][j], c);
                c = MFMA(a1, bfr[0][j], c);
                c = MFMA(a1, bfr[1][j], c);
                c = MFMA(a0, bfr[2][j], c);
                c = MFMA(a2, bfr[0][j], c);
                acc[i][j] = c;
            }
        }
    }
    // epilogue: C/D layout col=lane&15, row=quad*4+reg
#pragma unroll
    for (int i = 0; i < 4; ++i)
#pragma unroll
        for (int j = 0; j < 4; ++j) {
            int row = bm + wr + i * 16 + quad * 4;
            int col = bn + wc + j * 16 + l16;
            float* p = C + (size_t)row * TN + col;
#pragma unroll
            for (int r = 0; r < 4; ++r) p[(size_t)r * TN] = acc[i][j][r];
        }
}

// ---------------- single-product GEMM, 128x128, distance-2 prefetch ----------------
__global__ __launch_bounds__(256, 1) void gemm1_bf16(
    const unsigned short* __restrict__ A, const unsigned short* __restrict__ Bt,
    float* __restrict__ C) {
    __shared__ unsigned short lds[16 * 512];  // 16 KB
    const int tid = threadIdx.x;
    const int wave = tid >> 6, lane = tid & 63;
    const int wr = (wave >> 1) * 64, wc = (wave & 1) * 64;
    const int quad = lane >> 4, l16 = lane & 15;
    const int bm = blockIdx.y * 128, bn = blockIdx.x * 128;

    const int srow = lane >> 2;
    const int cg = ((lane & 3) - (lane >> 2) - (lane >> 4)) & 3;
    const unsigned short* sp[4];
#pragma unroll
    for (int t = 0; t < 4; ++t) {
        int s = wave * 4 + t;
        int isA = s < 8;
        int seg = isA ? s : (s - 8);
        const unsigned short* base = isA ? A : Bt;
        int gr = (isA ? bm : bn) + seg * 16 + srow;
        sp[t] = base + (size_t)gr * TN + cg * 8;
    }
    unsigned short* dbase = lds + wave * 4 * 512 + lane * 8;
    const int rdoff = l16 * 32 + ((quad + l16 + (l16 >> 2)) & 3) * 8;
    const unsigned short* rdA = lds + rdoff + (wr >> 4) * 512;
    const unsigned short* rdB = lds + rdoff + (8 + (wc >> 4)) * 512;

    f32x4 acc[4][4];
#pragma unroll
    for (int i = 0; i < 4; ++i)
#pragma unroll
        for (int j = 0; j < 4; ++j) acc[i][j] = (f32x4){0.f, 0.f, 0.f, 0.f};

    u32x4 g[2][4];
#pragma unroll
    for (int t = 0; t < 4; ++t) { g[0][t] = *(const u32x4*)sp[t]; sp[t] += 32; }
#pragma unroll
    for (int t = 0; t < 4; ++t) { g[1][t] = *(const u32x4*)sp[t]; sp[t] += 32; }

#pragma unroll 2
    for (int k0 = 0; k0 < 64; ++k0) {
        __syncthreads();
#pragma unroll
        for (int t = 0; t < 4; ++t) *(u32x4*)(dbase + t * 512) = g[k0 & 1][t];
        if (k0 < 62) {
#pragma unroll
            for (int t = 0; t < 4; ++t) { g[k0 & 1][t] = *(const u32x4*)sp[t]; sp[t] += 32; }
        }
        __syncthreads();

        s16x8 bfr[4];
#pragma unroll
        for (int j = 0; j < 4; ++j) bfr[j] = *(const s16x8*)(rdB + j * 512);
#pragma unroll
        for (int i = 0; i < 4; ++i) {
            s16x8 a0 = *(const s16x8*)(rdA + i * 512);
#pragma unroll
            for (int j = 0; j < 4; ++j)
                acc[i][j] = MFMA(a0, bfr[j], acc[i][j]);
        }
    }
#pragma unroll
    for (int i = 0; i < 4; ++i)
#pragma unroll
        for (int j = 0; j < 4; ++j) {
            int row = bm + wr + i * 16 + quad * 4;
            int col = bn + wc + j * 16 + l16;
            float* p = C + (size_t)row * TN + col;
#pragma unroll
            for (int r = 0; r < 4; ++r) p[(size_t)r * TN] = acc[i][j][r];
        }
}

// ---------------- softmax ----------------
__global__ void softmax_kernel(const float* __restrict__ S, unsigned short* __restrict__ P) {
    __shared__ float red[256];
    const int row = blockIdx.x, tid = threadIdx.x;
    const float* s = S + (size_t)row * TN;
    float m = -3.4e38f;
    for (int c = tid; c < TN; c += 256) m = fmaxf(m, s[c]);
    red[tid] = m; __syncthreads();
    for (int st = 128; st > 0; st >>= 1) { if (tid < st) red[tid] = fmaxf(red[tid], red[tid + st]); __syncthreads(); }
    m = red[0]; __syncthreads();
    float sum = 0.f;
    for (int c = tid; c < TN; c += 256) sum += expf(s[c] - m);
    red[tid] = sum; __syncthreads();
    for (int st = 128; st > 0; st >>= 1) { if (tid < st) red[tid] += red[tid + st]; __syncthreads(); }
    float inv = 1.f / red[0];
    unsigned short* p = P + (size_t)row * TN;
    for (int c = tid; c < TN; c += 256) p[c] = f2b(expf(s[c] - m) * inv);
}

extern "C" void kernel_launch(void* const* d_in, const int* in_sizes, int n_in,
                              void* d_out, int out_size, void* d_ws, size_t ws_size,
                              hipStream_t stream) {
    const float* x = (const float*)d_in[0];
    const float* q = (const float*)d_in[1];
    const float* k = (const float*)d_in[2];
    const float* v = (const float*)d_in[3];
    float* out = (float*)d_out;
    const size_t M = (size_t)TN * TN;

    float* F2 = (float*)d_ws;
    unsigned short* pl = (unsigned short*)(F2 + M);
    unsigned short *x0 = pl,        *x1 = pl + M,   *x2 = pl + 2*M;
    unsigned short *q0 = pl + 3*M,  *q1 = pl + 4*M, *q2 = pl + 5*M;
    unsigned short *k0 = pl + 6*M,  *k1 = pl + 7*M, *k2 = pl + 8*M;
    unsigned short *v0 = pl + 9*M;
    unsigned short *a0 = q0, *a1 = q1, *a2 = q2;   // reuse q planes
    unsigned short *b0 = k0, *b1 = k1, *b2 = k2;   // reuse k planes
    unsigned short *p0 = x1, *c0 = x2;             // reuse x1/x2 after B-chain

    dim3 bs(256);
    dim3 gsplit(TN * TN / 4 / 256);
    dim3 gt(TN / 64, TN / 64);
    dim3 gg(TN / 128, TN / 128);   // 16x16 = 256 blocks, 1/CU

    hipLaunchKernelGGL(split3_kernel,  gsplit, bs, 0, stream, x, x0, x1, x2);
    hipLaunchKernelGGL(split3t_kernel, gt,     bs, 0, stream, q, q0, q1, q2);
    hipLaunchKernelGGL(gemm6_bf16, gg, bs, 0, stream, x0, x1, x2, q0, q1, q2, out);
    hipLaunchKernelGGL(split3t_kernel, gt, bs, 0, stream, k, k0, k1, k2);
    hipLaunchKernelGGL(gemm6_bf16, gg, bs, 0, stream, x0, x1, x2, k0, k1, k2, F2);
    hipLaunchKernelGGL(split3_kernel,  gsplit, bs, 0, stream, out, a0, a1, a2);
    hipLaunchKernelGGL(split3t_kernel, gt,     bs, 0, stream, F2, b0, b1, b2);
    hipLaunchKernelGGL(gemm6_bf16, gg, bs, 0, stream, a0, a1, a2, b0, b1, b2, out);
    hipLaunchKernelGGL(softmax_kernel, dim3(TN), bs, 0, stream, out, p0);
    hipLaunchKernelGGL(cast1t_kernel, gt, bs, 0, stream, v, v0);
    hipLaunchKernelGGL(gemm1_bf16, gg, bs, 0, stream, x0, v0, F2);
    hipLaunchKernelGGL(cast1t_kernel, gt, bs, 0, stream, F2, c0);
    hipLaunchKernelGGL(gemm1_bf16, gg, bs, 0, stream, p0, c0, out);
}

// Round 4
// 519.997 us; speedup vs baseline: 2.7720x; 1.0809x over previous
//
#include <hip/hip_runtime.h>
#include <stdint.h>

// softmax((x@q)@(x@k)) @ (x@v), N=2048, fp32 in/out.
// R4: fp16 2-term error-split (3 products: t0t0 + 2^-12*(t0t1' + t1't0), t1 scaled
// by 4096 to stay in fp16 normal range; dual accumulators). K-split x2 -> grid 512
// (2 blocks/CU) with atomicAdd-f32 into memset-zeroed targets (2 addends,
// commutative = deterministic). LDS layout is lane-linear for BOTH staging writes
// and frag reads: segment slot s = (row=s&15, kchunk=s>>4) -> zero bank conflicts,
// zero swizzle VALU.

#define TN 2048

typedef float f32x4 __attribute__((ext_vector_type(4)));
typedef _Float16 f16;
typedef f16 f16x8 __attribute__((ext_vector_type(8)));
typedef f16 f16x4 __attribute__((ext_vector_type(4)));
typedef unsigned int u32x4 __attribute__((ext_vector_type(4)));

#define MFMA16(a, b, c) __builtin_amdgcn_mfma_f32_16x16x32_f16(a, b, c, 0, 0, 0)

// ---------------- split kernels: a ~= t0 + t1'/4096 ----------------
__global__ void split2_kernel(const float* __restrict__ in,
                              f16* __restrict__ t0, f16* __restrict__ t1) {
    int i = (blockIdx.x * 256 + threadIdx.x) * 4;
    f32x4 f = *(const f32x4*)(in + i);
    f16x4 o0, o1;
#pragma unroll
    for (int e = 0; e < 4; ++e) {
        float a = f[e];
        f16 h0 = (f16)a;                    // RNE v_cvt_f16_f32
        float r = (a - (float)h0) * 4096.f; // exact (Dekker) * exact pow2
        o0[e] = h0; o1[e] = (f16)r;
    }
    *(f16x4*)(t0 + i) = o0; *(f16x4*)(t1 + i) = o1;
}

// transposed: out[c][r] = split(in[r][c]), 64x64 LDS tile
__global__ void split2t_kernel(const float* __restrict__ in,
                               f16* __restrict__ t0, f16* __restrict__ t1) {
    __shared__ f16 s0[64][68], s1[64][68];
    int bc = blockIdx.x * 64, br = blockIdx.y * 64;
    int tx = threadIdx.x & 15, ty = threadIdx.x >> 4;
#pragma unroll
    for (int rr = 0; rr < 64; rr += 16) {
        int r = rr + ty;
        f32x4 f = *(const f32x4*)(in + (size_t)(br + r) * TN + bc + tx * 4);
#pragma unroll
        for (int e = 0; e < 4; ++e) {
            float a = f[e];
            f16 h0 = (f16)a;
            float rr2 = (a - (float)h0) * 4096.f;
            s0[tx * 4 + e][r] = h0; s1[tx * 4 + e][r] = (f16)rr2;
        }
    }
    __syncthreads();
#pragma unroll
    for (int rr = 0; rr < 64; rr += 16) {
        int c = rr + ty;
        f16x4 o0, o1;
#pragma unroll
        for (int e = 0; e < 4; ++e) { o0[e] = s0[c][tx*4+e]; o1[e] = s1[c][tx*4+e]; }
        size_t off = (size_t)(bc + c) * TN + br + tx * 4;
        *(f16x4*)(t0 + off) = o0; *(f16x4*)(t1 + off) = o1;
    }
}

__global__ void cast1t_kernel(const float* __restrict__ in, f16* __restrict__ t0) {
    __shared__ f16 s0[64][68];
    int bc = blockIdx.x * 64, br = blockIdx.y * 64;
    int tx = threadIdx.x & 15, ty = threadIdx.x >> 4;
#pragma unroll
    for (int rr = 0; rr < 64; rr += 16) {
        int r = rr + ty;
        f32x4 f = *(const f32x4*)(in + (size_t)(br + r) * TN + bc + tx * 4);
#pragma unroll
        for (int e = 0; e < 4; ++e) s0[tx * 4 + e][r] = (f16)f[e];
    }
    __syncthreads();
#pragma unroll
    for (int rr = 0; rr < 64; rr += 16) {
        int c = rr + ty;
        f16x4 o0;
#pragma unroll
        for (int e = 0; e < 4; ++e) o0[e] = s0[c][tx*4+e];
        *(f16x4*)(t0 + (size_t)(bc + c) * TN + br + tx * 4) = o0;
    }
}

// ---------------- 3-product split GEMM, 128x128 tile, K-split x2 ----------------
// C (+)= a0@b0 + (a0@b1 + a1@b0)/4096 via dual accumulators.
// LDS: 32 segments x 1KB. Segs 0-7: a0-plane, 8-15: a1, 16-23: b0, 24-31: b1.
// Segment slot s (16B) = (row s&15, kchunk s>>4). Staging lane w writes slot w
// with global (row=w&15, chunk=w>>4); frag read lane reads slot==lane. Lane-linear
// both ways -> no bank conflicts.
__global__ __launch_bounds__(256, 2) void gemm3_f16(
    const f16* __restrict__ a0p, const f16* __restrict__ a1p,
    const f16* __restrict__ b0p, const f16* __restrict__ b1p,
    float* __restrict__ C) {
    __shared__ f16 lds[32 * 512];  // 32 KB
    const int tid = threadIdx.x;
    const int wave = tid >> 6, lane = tid & 63;
    const int wr = (wave >> 1) * 64, wc = (wave & 1) * 64;
    const int quad = lane >> 4, l16 = lane & 15;
    const int bm = blockIdx.y * 128, bn = blockIdx.x * 128;
    const int kbase = blockIdx.z * 1024;

    // staging: wave stages segs wave*8 .. wave*8+7 (one full plane-slab)
    const f16* sp[8];
#pragma unroll
    for (int t = 0; t < 8; ++t) {
        int s = wave * 8 + t;
        const f16* base; int gr;
        if (s < 16) { base = (s & 8) ? a1p : a0p; gr = bm + (s & 7) * 16 + l16; }
        else        { base = (s & 8) ? b1p : b0p; gr = bn + (s & 7) * 16 + l16; }
        sp[t] = base + (size_t)gr * TN + kbase + quad * 8;
    }
    f16* dst = lds + (size_t)wave * 8 * 512 + lane * 8;
    const f16* rdb = lds + lane * 8;

    f32x4 acc1[4][4], acc2[4][4];
#pragma unroll
    for (int i = 0; i < 4; ++i)
#pragma unroll
        for (int j = 0; j < 4; ++j) {
            acc1[i][j] = (f32x4){0.f, 0.f, 0.f, 0.f};
            acc2[i][j] = (f32x4){0.f, 0.f, 0.f, 0.f};
        }

    u32x4 g[8];
#pragma unroll
    for (int t = 0; t < 8; ++t) { g[t] = *(const u32x4*)sp[t]; sp[t] += 32; }

    for (int step = 0; step < 32; ++step) {
        __syncthreads();
#pragma unroll
        for (int t = 0; t < 8; ++t) *(u32x4*)(dst + t * 512) = g[t];
        if (step < 31) {
#pragma unroll
            for (int t = 0; t < 8; ++t) { g[t] = *(const u32x4*)sp[t]; sp[t] += 32; }
        }
        __syncthreads();

        f16x8 b0f[4], b1f[4];
#pragma unroll
        for (int j = 0; j < 4; ++j) {
            b0f[j] = *(const f16x8*)(rdb + (16 + (wc >> 4) + j) * 512);
            b1f[j] = *(const f16x8*)(rdb + (24 + (wc >> 4) + j) * 512);
        }
#pragma unroll
        for (int i = 0; i < 4; ++i) {
            f16x8 a0f = *(const f16x8*)(rdb + ((wr >> 4) + i) * 512);
            f16x8 a1f = *(const f16x8*)(rdb + (8 + (wr >> 4) + i) * 512);
#pragma unroll
            for (int j = 0; j < 4; ++j) {
                acc1[i][j] = MFMA16(a0f, b0f[j], acc1[i][j]);
                acc2[i][j] = MFMA16(a0f, b1f[j], acc2[i][j]);
                acc2[i][j] = MFMA16(a1f, b0f[j], acc2[i][j]);
            }
        }
    }
    const float sc = 1.f / 4096.f;
#pragma unroll
    for (int i = 0; i < 4; ++i)
#pragma unroll
        for (int j = 0; j < 4; ++j) {
            int row = bm + wr + i * 16 + quad * 4;
            int col = bn + wc + j * 16 + l16;
            float* p = C + (size_t)row * TN + col;
#pragma unroll
            for (int r = 0; r < 4; ++r)
                atomicAdd(p + (size_t)r * TN, acc1[i][j][r] + acc2[i][j][r] * sc);
        }
}

// ---------------- single-product GEMM, same structure ----------------
__global__ __launch_bounds__(256, 2) void gemm1_f16(
    const f16* __restrict__ A, const f16* __restrict__ Bt,
    float* __restrict__ C) {
    __shared__ f16 lds[16 * 512];  // 16 KB
    const int tid = threadIdx.x;
    const int wave = tid >> 6, lane = tid & 63;
    const int wr = (wave >> 1) * 64, wc = (wave & 1) * 64;
    const int quad = lane >> 4, l16 = lane & 15;
    const int bm = blockIdx.y * 128, bn = blockIdx.x * 128;
    const int kbase = blockIdx.z * 1024;

    const f16* sp[4];
#pragma unroll
    for (int t = 0; t < 4; ++t) {
        int s = wave * 4 + t;
        const f16* base; int gr;
        if (s < 8) { base = A;  gr = bm + s * 16 + l16; }
        else       { base = Bt; gr = bn + (s - 8) * 16 + l16; }
        sp[t] = base + (size_t)gr * TN + kbase + quad * 8;
    }
    f16* dst = lds + (size_t)wave * 4 * 512 + lane * 8;
    const f16* rdb = lds + lane * 8;

    f32x4 acc[4][4];
#pragma unroll
    for (int i = 0; i < 4; ++i)
#pragma unroll
        for (int j = 0; j < 4; ++j) acc[i][j] = (f32x4){0.f, 0.f, 0.f, 0.f};

    u32x4 g[4];
#pragma unroll
    for (int t = 0; t < 4; ++t) { g[t] = *(const u32x4*)sp[t]; sp[t] += 32; }

    for (int step = 0; step < 32; ++step) {
        __syncthreads();
#pragma unroll
        for (int t = 0; t < 4; ++t) *(u32x4*)(dst + t * 512) = g[t];
        if (step < 31) {
#pragma unroll
            for (int t = 0; t < 4; ++t) { g[t] = *(const u32x4*)sp[t]; sp[t] += 32; }
        }
        __syncthreads();

        f16x8 bf[4];
#pragma unroll
        for (int j = 0; j < 4; ++j) bf[j] = *(const f16x8*)(rdb + (8 + (wc >> 4) + j) * 512);
#pragma unroll
        for (int i = 0; i < 4; ++i) {
            f16x8 af = *(const f16x8*)(rdb + ((wr >> 4) + i) * 512);
#pragma unroll
            for (int j = 0; j < 4; ++j) acc[i][j] = MFMA16(af, bf[j], acc[i][j]);
        }
    }
#pragma unroll
    for (int i = 0; i < 4; ++i)
#pragma unroll
        for (int j = 0; j < 4; ++j) {
            int row = bm + wr + i * 16 + quad * 4;
            int col = bn + wc + j * 16 + l16;
            float* p = C + (size_t)row * TN + col;
#pragma unroll
            for (int r = 0; r < 4; ++r) atomicAdd(p + (size_t)r * TN, acc[i][j][r]);
        }
}

// ---------------- softmax (fp32 in, fp16 P out) ----------------
__global__ void softmax_kernel(const float* __restrict__ S, f16* __restrict__ P) {
    __shared__ float red[256];
    const int row = blockIdx.x, tid = threadIdx.x;
    const float* s = S + (size_t)row * TN;
    float m = -3.4e38f;
    for (int c = tid; c < TN; c += 256) m = fmaxf(m, s[c]);
    red[tid] = m; __syncthreads();
    for (int st = 128; st > 0; st >>= 1) { if (tid < st) red[tid] = fmaxf(red[tid], red[tid + st]); __syncthreads(); }
    m = red[0]; __syncthreads();
    float sum = 0.f;
    for (int c = tid; c < TN; c += 256) sum += expf(s[c] - m);
    red[tid] = sum; __syncthreads();
    for (int st = 128; st > 0; st >>= 1) { if (tid < st) red[tid] += red[tid + st]; __syncthreads(); }
    float inv = 1.f / red[0];
    f16* p = P + (size_t)row * TN;
    for (int c = tid; c < TN; c += 256) p[c] = (f16)(expf(s[c] - m) * inv);
}

extern "C" void kernel_launch(void* const* d_in, const int* in_sizes, int n_in,
                              void* d_out, int out_size, void* d_ws, size_t ws_size,
                              hipStream_t stream) {
    const float* x = (const float*)d_in[0];
    const float* q = (const float*)d_in[1];
    const float* k = (const float*)d_in[2];
    const float* v = (const float*)d_in[3];
    float* out = (float*)d_out;
    const size_t M = (size_t)TN * TN;

    // ws: 2 fp32 scratch (33.6 MB) + 7 fp16 planes (58.8 MB) = 92.4 MB
    float* W1 = (float*)d_ws;
    float* W2 = W1 + M;
    f16* pl = (f16*)(W2 + M);
    f16 *x0 = pl,         *x1 = pl + M;
    f16 *q0 = pl + 2 * M, *q1 = pl + 3 * M;
    f16 *k0 = pl + 4 * M, *k1 = pl + 5 * M;
    f16 *v0 = pl + 6 * M;
    f16 *a0 = q0, *a1 = q1;   // reuse q planes after A split
    f16 *b0 = k0, *b1 = k1;   // reuse k planes after B split
    f16 *p0 = x1, *c0 = x0;   // x1 free after B-gemm; x0 free after x@v

    dim3 bs(256);
    dim3 gsplit(TN * TN / 4 / 256);
    dim3 gt(TN / 64, TN / 64);
    dim3 gg(TN / 128, TN / 128, 2);   // 16x16x2 = 512 blocks, 2/CU

    // A = x@q -> d_out (atomic, zeroed)
    hipMemsetAsync(d_out, 0, M * 4, stream);
    hipLaunchKernelGGL(split2_kernel,  gsplit, bs, 0, stream, x, x0, x1);
    hipLaunchKernelGGL(split2t_kernel, gt,     bs, 0, stream, q, q0, q1);
    hipLaunchKernelGGL(gemm3_f16, gg, bs, 0, stream, x0, x1, q0, q1, out);
    // B = x@k -> W1
    hipMemsetAsync(W1, 0, M * 4, stream);
    hipLaunchKernelGGL(split2t_kernel, gt, bs, 0, stream, k, k0, k1);
    hipLaunchKernelGGL(gemm3_f16, gg, bs, 0, stream, x0, x1, k0, k1, W1);
    // split A (d_out) and B (W1)
    hipLaunchKernelGGL(split2_kernel,  gsplit, bs, 0, stream, out, a0, a1);
    hipLaunchKernelGGL(split2t_kernel, gt,     bs, 0, stream, W1, b0, b1);
    // S = A@B -> W2
    hipMemsetAsync(W2, 0, M * 4, stream);
    hipLaunchKernelGGL(gemm3_f16, gg, bs, 0, stream, a0, a1, b0, b1, W2);
    // P = softmax(S) -> p0 (x1)
    hipLaunchKernelGGL(softmax_kernel, dim3(TN), bs, 0, stream, W2, p0);
    // C = x@v -> W1 (re-zeroed; b-planes already extracted)
    hipLaunchKernelGGL(cast1t_kernel, gt, bs, 0, stream, v, v0);
    hipMemsetAsync(W1, 0, M * 4, stream);
    hipLaunchKernelGGL(gemm1_f16, gg, bs, 0, stream, x0, v0, W1);
    hipLaunchKernelGGL(cast1t_kernel, gt, bs, 0, stream, W1, c0);
    // out = P@C -> d_out (re-zeroed)
    hipMemsetAsync(d_out, 0, M * 4, stream);
    hipLaunchKernelGGL(gemm1_f16, gg, bs, 0, stream, p0, c0, out);
}

// Round 5
// 515.860 us; speedup vs baseline: 2.7943x; 1.0080x over previous
//
#include <hip/hip_runtime.h>
#include <stdint.h>

// softmax((x@q)@(x@k)) @ (x@v), N=2048, fp32 in/out.
// R5: double-buffered LDS K-loop, ONE barrier/step, prefetch issued after the
// ds_write so the barrier's vmcnt drain lands a full MFMA region after load
// issue (fixes R4's per-step global-latency exposure). Numerics unchanged:
// fp16 2-term split, 3 products (t0t0 + 2^-12*(t0t1'+t1't0)), K-split x2 with
// atomicAdd into zeroed fp32. LDS layout lane-linear both ways (0 conflicts,
// verified R4).

#define TN 2048

typedef float f32x4 __attribute__((ext_vector_type(4)));
typedef _Float16 f16;
typedef f16 f16x8 __attribute__((ext_vector_type(8)));
typedef f16 f16x4 __attribute__((ext_vector_type(4)));
typedef unsigned int u32x4 __attribute__((ext_vector_type(4)));

#define MFMA16(a, b, c) __builtin_amdgcn_mfma_f32_16x16x32_f16(a, b, c, 0, 0, 0)

// ---------------- split kernels: a ~= t0 + t1'/4096 ----------------
__global__ void split2_kernel(const float* __restrict__ in,
                              f16* __restrict__ t0, f16* __restrict__ t1) {
    int i = (blockIdx.x * 256 + threadIdx.x) * 4;
    f32x4 f = *(const f32x4*)(in + i);
    f16x4 o0, o1;
#pragma unroll
    for (int e = 0; e < 4; ++e) {
        float a = f[e];
        f16 h0 = (f16)a;
        float r = (a - (float)h0) * 4096.f;
        o0[e] = h0; o1[e] = (f16)r;
    }
    *(f16x4*)(t0 + i) = o0; *(f16x4*)(t1 + i) = o1;
}

__global__ void split2t_kernel(const float* __restrict__ in,
                               f16* __restrict__ t0, f16* __restrict__ t1) {
    __shared__ f16 s0[64][68], s1[64][68];
    int bc = blockIdx.x * 64, br = blockIdx.y * 64;
    int tx = threadIdx.x & 15, ty = threadIdx.x >> 4;
#pragma unroll
    for (int rr = 0; rr < 64; rr += 16) {
        int r = rr + ty;
        f32x4 f = *(const f32x4*)(in + (size_t)(br + r) * TN + bc + tx * 4);
#pragma unroll
        for (int e = 0; e < 4; ++e) {
            float a = f[e];
            f16 h0 = (f16)a;
            float rr2 = (a - (float)h0) * 4096.f;
            s0[tx * 4 + e][r] = h0; s1[tx * 4 + e][r] = (f16)rr2;
        }
    }
    __syncthreads();
#pragma unroll
    for (int rr = 0; rr < 64; rr += 16) {
        int c = rr + ty;
        f16x4 o0, o1;
#pragma unroll
        for (int e = 0; e < 4; ++e) { o0[e] = s0[c][tx*4+e]; o1[e] = s1[c][tx*4+e]; }
        size_t off = (size_t)(bc + c) * TN + br + tx * 4;
        *(f16x4*)(t0 + off) = o0; *(f16x4*)(t1 + off) = o1;
    }
}

__global__ void cast1t_kernel(const float* __restrict__ in, f16* __restrict__ t0) {
    __shared__ f16 s0[64][68];
    int bc = blockIdx.x * 64, br = blockIdx.y * 64;
    int tx = threadIdx.x & 15, ty = threadIdx.x >> 4;
#pragma unroll
    for (int rr = 0; rr < 64; rr += 16) {
        int r = rr + ty;
        f32x4 f = *(const f32x4*)(in + (size_t)(br + r) * TN + bc + tx * 4);
#pragma unroll
        for (int e = 0; e < 4; ++e) s0[tx * 4 + e][r] = (f16)f[e];
    }
    __syncthreads();
#pragma unroll
    for (int rr = 0; rr < 64; rr += 16) {
        int c = rr + ty;
        f16x4 o0;
#pragma unroll
        for (int e = 0; e < 4; ++e) o0[e] = s0[c][tx*4+e];
        *(f16x4*)(t0 + (size_t)(bc + c) * TN + br + tx * 4) = o0;
    }
}

// ---------------- 3-product split GEMM, 128x128, K-split x2, double-buffered ----------------
// Per iter: barrier; read frags from buf[p]; write buf[1-p] from g (loaded a full
// iter ago); issue prefetch for iter+2; 48 MFMA. Single barrier covers both LDS
// hazards (lgkm in-order + __syncthreads drain).
__global__ __launch_bounds__(256, 2) void gemm3_f16(
    const f16* __restrict__ a0p, const f16* __restrict__ a1p,
    const f16* __restrict__ b0p, const f16* __restrict__ b1p,
    float* __restrict__ C) {
    __shared__ f16 lds[2][32 * 512];  // 64 KB
    const int tid = threadIdx.x;
    const int wave = tid >> 6, lane = tid & 63;
    const int wr = (wave >> 1) * 64, wc = (wave & 1) * 64;
    const int quad = lane >> 4, l16 = lane & 15;
    const int bm = blockIdx.y * 128, bn = blockIdx.x * 128;
    const int kbase = blockIdx.z * 1024;

    const f16* sp[8];
#pragma unroll
    for (int t = 0; t < 8; ++t) {
        int s = wave * 8 + t;
        const f16* base; int gr;
        if (s < 16) { base = (s & 8) ? a1p : a0p; gr = bm + (s & 7) * 16 + l16; }
        else        { base = (s & 8) ? b1p : b0p; gr = bn + (s & 7) * 16 + l16; }
        sp[t] = base + (size_t)gr * TN + kbase + quad * 8;
    }
    const int dof = wave * 8 * 512 + lane * 8;  // staging offset within buffer
    const int rof = lane * 8;                   // read offset within segment

    f32x4 acc1[4][4], acc2[4][4];
#pragma unroll
    for (int i = 0; i < 4; ++i)
#pragma unroll
        for (int j = 0; j < 4; ++j) {
            acc1[i][j] = (f32x4){0.f, 0.f, 0.f, 0.f};
            acc2[i][j] = (f32x4){0.f, 0.f, 0.f, 0.f};
        }

    u32x4 g[8];
    // prologue: step0 -> buf0; prefetch step1 into g
#pragma unroll
    for (int t = 0; t < 8; ++t) { g[t] = *(const u32x4*)sp[t]; sp[t] += 32; }
#pragma unroll
    for (int t = 0; t < 8; ++t) *(u32x4*)(&lds[0][0] + dof + t * 512) = g[t];
#pragma unroll
    for (int t = 0; t < 8; ++t) { g[t] = *(const u32x4*)sp[t]; sp[t] += 32; }

    for (int step = 0; step < 32; ++step) {
        const int p = step & 1;
        __syncthreads();
        const f16* rdb = &lds[p][0] + rof;
        f16x8 b0f[4], b1f[4], a0f[4], a1f[4];
#pragma unroll
        for (int j = 0; j < 4; ++j) {
            b0f[j] = *(const f16x8*)(rdb + (16 + (wc >> 4) + j) * 512);
            b1f[j] = *(const f16x8*)(rdb + (24 + (wc >> 4) + j) * 512);
        }
#pragma unroll
        for (int i = 0; i < 4; ++i) {
            a0f[i] = *(const f16x8*)(rdb + ((wr >> 4) + i) * 512);
            a1f[i] = *(const f16x8*)(rdb + (8 + (wr >> 4) + i) * 512);
        }
        if (step < 31) {
            f16* dst = &lds[1 - p][0] + dof;
#pragma unroll
            for (int t = 0; t < 8; ++t) *(u32x4*)(dst + t * 512) = g[t];
        }
        if (step < 30) {
#pragma unroll
            for (int t = 0; t < 8; ++t) { g[t] = *(const u32x4*)sp[t]; sp[t] += 32; }
        }
#pragma unroll
        for (int i = 0; i < 4; ++i)
#pragma unroll
            for (int j = 0; j < 4; ++j) {
                acc1[i][j] = MFMA16(a0f[i], b0f[j], acc1[i][j]);
                acc2[i][j] = MFMA16(a0f[i], b1f[j], acc2[i][j]);
                acc2[i][j] = MFMA16(a1f[i], b0f[j], acc2[i][j]);
            }
    }
    const float sc = 1.f / 4096.f;
#pragma unroll
    for (int i = 0; i < 4; ++i)
#pragma unroll
        for (int j = 0; j < 4; ++j) {
            int row = bm + wr + i * 16 + quad * 4;
            int col = bn + wc + j * 16 + l16;
            float* p = C + (size_t)row * TN + col;
#pragma unroll
            for (int r = 0; r < 4; ++r)
                atomicAdd(p + (size_t)r * TN, acc1[i][j][r] + acc2[i][j][r] * sc);
        }
}

// ---------------- single-product GEMM, double-buffered ----------------
__global__ __launch_bounds__(256, 2) void gemm1_f16(
    const f16* __restrict__ A, const f16* __restrict__ Bt,
    float* __restrict__ C) {
    __shared__ f16 lds[2][16 * 512];  // 32 KB
    const int tid = threadIdx.x;
    const int wave = tid >> 6, lane = tid & 63;
    const int wr = (wave >> 1) * 64, wc = (wave & 1) * 64;
    const int quad = lane >> 4, l16 = lane & 15;
    const int bm = blockIdx.y * 128, bn = blockIdx.x * 128;
    const int kbase = blockIdx.z * 1024;

    const f16* sp[4];
#pragma unroll
    for (int t = 0; t < 4; ++t) {
        int s = wave * 4 + t;
        const f16* base; int gr;
        if (s < 8) { base = A;  gr = bm + s * 16 + l16; }
        else       { base = Bt; gr = bn + (s - 8) * 16 + l16; }
        sp[t] = base + (size_t)gr * TN + kbase + quad * 8;
    }
    const int dof = wave * 4 * 512 + lane * 8;
    const int rof = lane * 8;

    f32x4 acc[4][4];
#pragma unroll
    for (int i = 0; i < 4; ++i)
#pragma unroll
        for (int j = 0; j < 4; ++j) acc[i][j] = (f32x4){0.f, 0.f, 0.f, 0.f};

    u32x4 g[4];
#pragma unroll
    for (int t = 0; t < 4; ++t) { g[t] = *(const u32x4*)sp[t]; sp[t] += 32; }
#pragma unroll
    for (int t = 0; t < 4; ++t) *(u32x4*)(&lds[0][0] + dof + t * 512) = g[t];
#pragma unroll
    for (int t = 0; t < 4; ++t) { g[t] = *(const u32x4*)sp[t]; sp[t] += 32; }

    for (int step = 0; step < 32; ++step) {
        const int p = step & 1;
        __syncthreads();
        const f16* rdb = &lds[p][0] + rof;
        f16x8 bf[4], af[4];
#pragma unroll
        for (int j = 0; j < 4; ++j) bf[j] = *(const f16x8*)(rdb + (8 + (wc >> 4) + j) * 512);
#pragma unroll
        for (int i = 0; i < 4; ++i) af[i] = *(const f16x8*)(rdb + ((wr >> 4) + i) * 512);
        if (step < 31) {
            f16* dst = &lds[1 - p][0] + dof;
#pragma unroll
            for (int t = 0; t < 4; ++t) *(u32x4*)(dst + t * 512) = g[t];
        }
        if (step < 30) {
#pragma unroll
            for (int t = 0; t < 4; ++t) { g[t] = *(const u32x4*)sp[t]; sp[t] += 32; }
        }
#pragma unroll
        for (int i = 0; i < 4; ++i)
#pragma unroll
            for (int j = 0; j < 4; ++j) acc[i][j] = MFMA16(af[i], bf[j], acc[i][j]);
    }
#pragma unroll
    for (int i = 0; i < 4; ++i)
#pragma unroll
        for (int j = 0; j < 4; ++j) {
            int row = bm + wr + i * 16 + quad * 4;
            int col = bn + wc + j * 16 + l16;
            float* p = C + (size_t)row * TN + col;
#pragma unroll
            for (int r = 0; r < 4; ++r) atomicAdd(p + (size_t)r * TN, acc[i][j][r]);
        }
}

// ---------------- softmax (fp32 in, fp16 P out) ----------------
__global__ void softmax_kernel(const float* __restrict__ S, f16* __restrict__ P) {
    __shared__ float red[256];
    const int row = blockIdx.x, tid = threadIdx.x;
    const float* s = S + (size_t)row * TN;
    float m = -3.4e38f;
    for (int c = tid; c < TN; c += 256) m = fmaxf(m, s[c]);
    red[tid] = m; __syncthreads();
    for (int st = 128; st > 0; st >>= 1) { if (tid < st) red[tid] = fmaxf(red[tid], red[tid + st]); __syncthreads(); }
    m = red[0]; __syncthreads();
    float sum = 0.f;
    for (int c = tid; c < TN; c += 256) sum += expf(s[c] - m);
    red[tid] = sum; __syncthreads();
    for (int st = 128; st > 0; st >>= 1) { if (tid < st) red[tid] += red[tid + st]; __syncthreads(); }
    float inv = 1.f / red[0];
    f16* p = P + (size_t)row * TN;
    for (int c = tid; c < TN; c += 256) p[c] = (f16)(expf(s[c] - m) * inv);
}

extern "C" void kernel_launch(void* const* d_in, const int* in_sizes, int n_in,
                              void* d_out, int out_size, void* d_ws, size_t ws_size,
                              hipStream_t stream) {
    const float* x = (const float*)d_in[0];
    const float* q = (const float*)d_in[1];
    const float* k = (const float*)d_in[2];
    const float* v = (const float*)d_in[3];
    float* out = (float*)d_out;
    const size_t M = (size_t)TN * TN;

    float* W1 = (float*)d_ws;
    float* W2 = W1 + M;
    f16* pl = (f16*)(W2 + M);
    f16 *x0 = pl,         *x1 = pl + M;
    f16 *q0 = pl + 2 * M, *q1 = pl + 3 * M;
    f16 *k0 = pl + 4 * M, *k1 = pl + 5 * M;
    f16 *v0 = pl + 6 * M;
    f16 *a0 = q0, *a1 = q1;
    f16 *b0 = k0, *b1 = k1;
    f16 *p0 = x1, *c0 = x0;

    dim3 bs(256);
    dim3 gsplit(TN * TN / 4 / 256);
    dim3 gt(TN / 64, TN / 64);
    dim3 gg(TN / 128, TN / 128, 2);   // 512 blocks, 2/CU

    hipMemsetAsync(d_out, 0, M * 4, stream);
    hipLaunchKernelGGL(split2_kernel,  gsplit, bs, 0, stream, x, x0, x1);
    hipLaunchKernelGGL(split2t_kernel, gt,     bs, 0, stream, q, q0, q1);
    hipLaunchKernelGGL(gemm3_f16, gg, bs, 0, stream, x0, x1, q0, q1, out);
    hipMemsetAsync(W1, 0, M * 4, stream);
    hipLaunchKernelGGL(split2t_kernel, gt, bs, 0, stream, k, k0, k1);
    hipLaunchKernelGGL(gemm3_f16, gg, bs, 0, stream, x0, x1, k0, k1, W1);
    hipLaunchKernelGGL(split2_kernel,  gsplit, bs, 0, stream, out, a0, a1);
    hipLaunchKernelGGL(split2t_kernel, gt,     bs, 0, stream, W1, b0, b1);
    hipMemsetAsync(W2, 0, M * 4, stream);
    hipLaunchKernelGGL(gemm3_f16, gg, bs, 0, stream, a0, a1, b0, b1, W2);
    hipLaunchKernelGGL(softmax_kernel, dim3(TN), bs, 0, stream, W2, p0);
    hipLaunchKernelGGL(cast1t_kernel, gt, bs, 0, stream, v, v0);
    hipMemsetAsync(W1, 0, M * 4, stream);
    hipLaunchKernelGGL(gemm1_f16, gg, bs, 0, stream, x0, v0, W1);
    hipLaunchKernelGGL(cast1t_kernel, gt, bs, 0, stream, W1, c0);
    hipMemsetAsync(d_out, 0, M * 4, stream);
    hipLaunchKernelGGL(gemm1_f16, gg, bs, 0, stream, p0, c0, out);
}